// Round 8
// baseline (496.695 us; speedup 1.0000x reference)
//
#include <hip/hip_runtime.h>
#include <hip/hip_bf16.h>

typedef __attribute__((ext_vector_type(8))) short short8;
typedef __attribute__((ext_vector_type(4))) short short4v;
typedef __attribute__((ext_vector_type(4))) float f32x4;
typedef __attribute__((ext_vector_type(4))) int i32x4;
typedef __attribute__((ext_vector_type(4))) unsigned u32x4;

#define NR 8192
#define LOG2E 1.4426950408889634f
#define TSTRIDE 40              // shorts per f-row in a tile (padded; 80 B, 16B-aligned)
#define TILESH (128 * TSTRIDE)  // 5120 shorts = 10240 B per j-tile

__device__ __forceinline__ short f2bf(float f) {
  return __builtin_bit_cast(short, __float2bfloat16(f));
}

// ---------------------------------------------------------------------------
// K0: pack adj (int32 0/1, 256 MB) -> bitmask (8 MB). Pure streaming.
// Nontemporal: adj is read once, mask is single-use later -> keep L2 clean.
// ---------------------------------------------------------------------------
__global__ __launch_bounds__(256) void k_pack(const int* __restrict__ adj,
                                              unsigned* __restrict__ mask) {
  size_t gid = (size_t)blockIdx.x * 256 + threadIdx.x;  // word index, 2M total
  const i32x4* p = (const i32x4*)&adj[gid * 32];
  unsigned m = 0;
#pragma unroll
  for (int c = 0; c < 8; ++c) {
    i32x4 v = __builtin_nontemporal_load(&p[c]);
    m |= (unsigned)(v.x > 0) << (c * 4 + 0);
    m |= (unsigned)(v.y > 0) << (c * 4 + 1);
    m |= (unsigned)(v.z > 0) << (c * 4 + 2);
    m |= (unsigned)(v.w > 0) << (c * 4 + 3);
  }
  __builtin_nontemporal_store(m, &mask[gid]);
}

// ---------------------------------------------------------------------------
// K1: HT2 = (x @ W)^T in bf16, padded-tile layout HT2[j>>5][f][j&31],
// f-stride TSTRIDE. Fused s,t epilogue. (unchanged, ~10 us)
// ---------------------------------------------------------------------------
__global__ __launch_bounds__(256) void k_gemm_h(const float* __restrict__ x,
                                                const float* __restrict__ W,
                                                const float* __restrict__ a,
                                                short* __restrict__ HT2,
                                                float* __restrict__ sv,
                                                float* __restrict__ tv) {
  __shared__ short WT[128][136];  // pad 8 shorts -> 2-way alias (free, m136)
  const int tid = threadIdx.x;
  const int w = tid >> 6;
  const int L = tid & 63;
  const int lm = L & 15;
  const int q = L >> 4;
  const int i0 = blockIdx.x * 64;

  f32x4 acc[8];
#pragma unroll
  for (int nn = 0; nn < 8; ++nn) acc[nn] = (f32x4){0.f, 0.f, 0.f, 0.f};

  for (int kc = 0; kc < 256; kc += 128) {
    if (kc) __syncthreads();
#pragma unroll
    for (int p = 0; p < 16; ++p) {
      int idx = p * 256 + tid;  // 0..4095
      int k = idx >> 5;         // 0..127
      int f4 = (idx & 31) * 4;
      float4 v = *(const float4*)&W[(kc + k) * 128 + f4];
      WT[f4 + 0][k] = f2bf(v.x);
      WT[f4 + 1][k] = f2bf(v.y);
      WT[f4 + 2][k] = f2bf(v.z);
      WT[f4 + 3][k] = f2bf(v.w);
    }
    __syncthreads();
#pragma unroll
    for (int ks = 0; ks < 4; ++ks) {
      int row = i0 + 16 * w + lm;
      const float* xp = &x[(size_t)row * 256 + kc + ks * 32 + q * 8];
      float4 xa = *(const float4*)xp;
      float4 xb = *(const float4*)(xp + 4);
      short8 af;
      af[0] = f2bf(xa.x); af[1] = f2bf(xa.y); af[2] = f2bf(xa.z); af[3] = f2bf(xa.w);
      af[4] = f2bf(xb.x); af[5] = f2bf(xb.y); af[6] = f2bf(xb.z); af[7] = f2bf(xb.w);
#pragma unroll
      for (int nn = 0; nn < 8; ++nn) {
        short8 bf = *(const short8*)&WT[nn * 16 + lm][ks * 32 + q * 8];
        acc[nn] = __builtin_amdgcn_mfma_f32_16x16x32_bf16(af, bf, acc[nn], 0, 0, 0);
      }
    }
  }

  const int ib = i0 + 16 * w + 4 * q;  // this thread's 4 output j-rows
  const int tbase = (ib >> 5) * TILESH + (ib & 31);
  float a1v[8], a2v[8];
#pragma unroll
  for (int nn = 0; nn < 8; ++nn) {
    a1v[nn] = a[nn * 16 + lm];
    a2v[nn] = a[128 + nn * 16 + lm];
  }
  float sr[4] = {0.f, 0.f, 0.f, 0.f};
  float tr[4] = {0.f, 0.f, 0.f, 0.f};
#pragma unroll
  for (int nn = 0; nn < 8; ++nn) {
    int f = nn * 16 + lm;
    short4v o;
    o[0] = f2bf(acc[nn][0]);
    o[1] = f2bf(acc[nn][1]);
    o[2] = f2bf(acc[nn][2]);
    o[3] = f2bf(acc[nn][3]);
    *(short4v*)&HT2[tbase + f * TSTRIDE] = o;
#pragma unroll
    for (int r = 0; r < 4; ++r) {
      sr[r] += acc[nn][r] * a1v[nn];
      tr[r] += acc[nn][r] * a2v[nn];
    }
  }
#pragma unroll
  for (int d = 1; d < 16; d <<= 1) {
#pragma unroll
    for (int r = 0; r < 4; ++r) {
      sr[r] += __shfl_xor(sr[r], d);
      tr[r] += __shfl_xor(tr[r], d);
    }
  }
  if (lm == 0) {
#pragma unroll
    for (int r = 0; r < 4; ++r) {
      sv[ib + r] = sr[r] * LOG2E;
      tv[ib + r] = tr[r] * LOG2E;
    }
  }
}

// ---------------------------------------------------------------------------
// K3: flash-GAT, m97-style block tiling + register-staged LDS double buffer.
// All single-use streams (mask in, part out) are NONTEMPORAL so the 2.5 MB
// HT2 working set stays L2-resident (theory: part/mask streaming was
// evicting it, turning the per-tile prefetch window into ~900-cyc HBM
// stalls). Mask is register-prefetched one group ahead.
// ---------------------------------------------------------------------------
__global__ __launch_bounds__(256, 3) void k_flash(const unsigned* __restrict__ mask,
                                                  const short* __restrict__ HT2,
                                                  const float* __restrict__ sv,
                                                  const float* __restrict__ tv,
                                                  float* __restrict__ part,
                                                  float* __restrict__ lpart,
                                                  int S) {
  __shared__ __align__(16) char smem[32768];  // 2x10KB stage bufs; epilogue 4x8KB
  short* const buf0 = (short*)smem;
  short* const buf1 = (short*)(smem + 10240);
  const int tid = threadIdx.x;
  const int w = tid >> 6;
  const int L = tid & 63;
  const int lm = L & 15;
  const int q = L >> 4;
  const int sp = blockIdx.x >> 6;  // 64 i-tiles of 128 rows
  const int it = blockIdx.x & 63;
  const int i0 = it * 128;

  const int row0 = i0 + 32 * w + lm;
  const int row1 = row0 + 16;
  const float s0 = sv[row0];
  const float s1 = sv[row1];

  f32x4 acc[2][8];
#pragma unroll
  for (int mm = 0; mm < 2; ++mm)
#pragma unroll
    for (int nn = 0; nn < 8; ++nn) acc[mm][nn] = (f32x4){0.f, 0.f, 0.f, 0.f};
  float l0 = 0.f, l1 = 0.f;

  const int JR = NR / S;
  const int T = JR >> 5;  // j-tiles per block
  const int tile0 = (sp * JR) >> 5;

  // prologue: stage tile0 + prefetch first mask group
  const uint4* gs = (const uint4*)(HT2 + (size_t)tile0 * TILESH);
  uint4 r0 = gs[tid], r1 = gs[256 + tid], r2 = {};
  if (tid < 128) r2 = gs[512 + tid];
  {
    uint4* d = (uint4*)buf0;
    d[tid] = r0; d[256 + tid] = r1;
    if (tid < 128) d[512 + tid] = r2;
  }
  u32x4 mn0 = __builtin_nontemporal_load((const u32x4*)&mask[row0 * 256 + tile0]);
  u32x4 mn1 = __builtin_nontemporal_load((const u32x4*)&mask[row1 * 256 + tile0]);

  unsigned mwa0[4], mwa1[4];
#pragma unroll 2
  for (int t = 0; t < T; ++t) {
    __syncthreads();  // buf[t&1] staged
    if (t + 1 < T) {  // issue next tile's global loads NOW (in flight over compute)
      gs = (const uint4*)(HT2 + (size_t)(tile0 + t + 1) * TILESH);
      r0 = gs[tid]; r1 = gs[256 + tid];
      if (tid < 128) r2 = gs[512 + tid];
    }
    if ((t & 3) == 0) {  // consume prefetched mask group; prefetch the next
      mwa0[0] = mn0.x; mwa0[1] = mn0.y; mwa0[2] = mn0.z; mwa0[3] = mn0.w;
      mwa1[0] = mn1.x; mwa1[1] = mn1.y; mwa1[2] = mn1.z; mwa1[3] = mn1.w;
      if (t + 4 < T) {
        mn0 = __builtin_nontemporal_load((const u32x4*)&mask[row0 * 256 + tile0 + t + 4]);
        mn1 = __builtin_nontemporal_load((const u32x4*)&mask[row1 * 256 + tile0 + t + 4]);
      }
    }
    const short* bp = (t & 1) ? buf1 : buf0;
    const int jb = (tile0 + t) * 32 + q * 8;
    float4 tv0 = *(const float4*)&tv[jb];
    float4 tv1 = *(const float4*)&tv[jb + 4];
    short8 bf[8];
#pragma unroll
    for (int nn = 0; nn < 8; ++nn)
      bf[nn] = *(const short8*)&bp[(nn * 16 + lm) * TSTRIDE + q * 8];

    const unsigned b0 = (mwa0[t & 3] >> (q * 8)) & 0xffu;
    const unsigned b1 = (mwa1[t & 3] >> (q * 8)) & 0xffu;
    float tvl[8] = {tv0.x, tv0.y, tv0.z, tv0.w, tv1.x, tv1.y, tv1.z, tv1.w};
    short8 p0, p1;
#pragma unroll
    for (int e = 0; e < 8; ++e) {
      // logits pre-scaled by log2e; lrelu(v) = max(v, 0.2v)
      float v0 = s0 + tvl[e];
      float e0 = fmaxf(v0, 0.2f * v0);
      float pp0 = (b0 & (1u << e)) ? __builtin_amdgcn_exp2f(e0) : 0.f;
      l0 += pp0;
      p0[e] = f2bf(pp0);
      float v1 = s1 + tvl[e];
      float e1 = fmaxf(v1, 0.2f * v1);
      float pp1 = (b1 & (1u << e)) ? __builtin_amdgcn_exp2f(e1) : 0.f;
      l1 += pp1;
      p1[e] = f2bf(pp1);
    }
#pragma unroll
    for (int nn = 0; nn < 8; ++nn) {
      acc[0][nn] = __builtin_amdgcn_mfma_f32_16x16x32_bf16(p0, bf[nn], acc[0][nn], 0, 0, 0);
      acc[1][nn] = __builtin_amdgcn_mfma_f32_16x16x32_bf16(p1, bf[nn], acc[1][nn], 0, 0, 0);
    }
    if (t + 1 < T) {  // commit staged regs to the other buffer
      uint4* d = (uint4*)((t & 1) ? buf0 : buf1);
      d[tid] = r0; d[256 + tid] = r1;
      if (tid < 128) d[512 + tid] = r2;
    }
  }
  __syncthreads();  // stage bufs free -> reuse LDS for epilogue

  // epilogue: wave-private LDS transpose, 2 chunks of 16 rows (8 KB/wave);
  // part stores nontemporal (single-use stream, keep L2 for HT2)
  float* my = (float*)(smem + w * 8192);
#pragma unroll
  for (int mm = 0; mm < 2; ++mm) {
#pragma unroll
    for (int nn = 0; nn < 8; ++nn)
#pragma unroll
      for (int r = 0; r < 4; ++r)
        my[(4 * q + r) * 128 + nn * 16 + lm] = acc[mm][nn][r];
    float* pbase = part + ((size_t)sp * NR + i0 + 32 * w + 16 * mm) * 128;
#pragma unroll
    for (int c = 0; c < 8; ++c) {
      int idx = (c * 64 + L) * 4;
      f32x4 v = *(const f32x4*)&my[idx];
      __builtin_nontemporal_store(v, (f32x4*)&pbase[idx]);
    }
  }

  // denominator: reduce the 4 q-replicas of each row
  l0 += __shfl_xor(l0, 16);
  l0 += __shfl_xor(l0, 32);
  l1 += __shfl_xor(l1, 16);
  l1 += __shfl_xor(l1, 32);
  if (q == 0) {
    lpart[sp * NR + row0] = l0;
    lpart[sp * NR + row1] = l1;
  }
}

// ---------------------------------------------------------------------------
// K4: out[i][f] = sum_sp part / sum_sp lpart (float4, nontemporal part reads)
// ---------------------------------------------------------------------------
__global__ __launch_bounds__(256) void k_reduce(const float* __restrict__ part,
                                                const float* __restrict__ lpart,
                                                float* __restrict__ out, int S) {
  int idx4 = blockIdx.x * 256 + threadIdx.x;
  int idx = idx4 * 4;  // i*128+f
  int i = idx >> 7;
  f32x4 sum = {0.f, 0.f, 0.f, 0.f};
  for (int sp = 0; sp < S; ++sp) {
    f32x4 v = __builtin_nontemporal_load((const f32x4*)&part[(size_t)sp * (NR * 128) + idx]);
    sum += v;
  }
  float l = 0.f;
  for (int sp = 0; sp < S; ++sp) l += lpart[sp * NR + i];
  float inv = (l > 0.f) ? 1.f / l : 0.f;
  f32x4 o = sum * inv;
  *(f32x4*)&out[idx] = o;
}

extern "C" void kernel_launch(void* const* d_in, const int* in_sizes, int n_in,
                              void* d_out, int out_size, void* d_ws, size_t ws_size,
                              hipStream_t stream) {
  const float* x = (const float*)d_in[0];    // 8192 x 256 fp32
  const int* adj = (const int*)d_in[1];      // 8192 x 8192 int32
  const float* W = (const float*)d_in[2];    // 256 x 128 fp32
  const float* a = (const float*)d_in[3];    // 256 x 1 fp32
  float* out = (float*)d_out;                // 8192 x 128 fp32

  char* ws = (char*)d_ws;
  short* HT2 = (short*)(ws + 0);               // 2.5 MB bf16 h, padded tiles [256][128][40]
  float* sv = (float*)(ws + 2621440);          // 32 KB
  float* tv = (float*)(ws + 2654208);          // 32 KB
  float* lpart = (float*)(ws + 2686976);       // <= 16*32 KB = 512 KB
  unsigned* mask = (unsigned*)(ws + 3211264);  // 8 MB bitmask [8192][256 words]
  float* part = (float*)(ws + 11599872);       // S * 4 MB

  int S = 16;  // j-splits: 1024 blocks, 3 resident blocks/CU (12 waves/CU)
  while (S > 1 && (size_t)11599872 + (size_t)S * 4194304 > ws_size) S >>= 1;

  hipLaunchKernelGGL(k_pack, dim3((NR * NR / 32) / 256), dim3(256), 0, stream, adj, mask);
  hipLaunchKernelGGL(k_gemm_h, dim3(128), dim3(256), 0, stream, x, W, a, HT2, sv, tv);
  hipLaunchKernelGGL(k_flash, dim3(64 * S), dim3(256), 0, stream, mask, HT2, sv, tv,
                     part, lpart, S);
  hipLaunchKernelGGL(k_reduce, dim3((NR * 128) / 1024), dim3(256), 0, stream, part,
                     lpart, out, S);
}

// Round 9
// 440.889 us; speedup vs baseline: 1.1266x; 1.1266x over previous
//
#include <hip/hip_runtime.h>
#include <hip/hip_bf16.h>

typedef __attribute__((ext_vector_type(8))) short short8;
typedef __attribute__((ext_vector_type(4))) short short4v;
typedef __attribute__((ext_vector_type(4))) float f32x4;

#define NR 8192
#define LOG2E 1.4426950408889634f

__device__ __forceinline__ short f2bf(float f) {
  return __builtin_bit_cast(short, __float2bfloat16(f));
}

// ---------------------------------------------------------------------------
// K0: pack adj (int32 0/1, 256 MB) -> bitmask (8 MB). Pure streaming,
// dependence-free -> HBM-saturating (~45 us, measured).
// ---------------------------------------------------------------------------
__global__ __launch_bounds__(256) void k_pack(const int* __restrict__ adj,
                                              unsigned* __restrict__ mask) {
  size_t gid = (size_t)blockIdx.x * 256 + threadIdx.x;  // word index, 2M total
  const int4* p = (const int4*)&adj[gid * 32];
  unsigned m = 0;
#pragma unroll
  for (int c = 0; c < 8; ++c) {
    int4 v = p[c];
    m |= (unsigned)(v.x > 0) << (c * 4 + 0);
    m |= (unsigned)(v.y > 0) << (c * 4 + 1);
    m |= (unsigned)(v.z > 0) << (c * 4 + 2);
    m |= (unsigned)(v.w > 0) << (c * 4 + 3);
  }
  mask[gid] = m;
}

// ---------------------------------------------------------------------------
// K1: HT2 = (x @ W)^T in bf16, tiled layout HT2[j>>5][f][j&31] (unpadded,
// tile = 128x32 bf16 = 8 KB) so k_flash B-frag loads are one contiguous
// 1 KB segment per instruction. Fused s,t epilogue. ~10 us.
// ---------------------------------------------------------------------------
__global__ __launch_bounds__(256) void k_gemm_h(const float* __restrict__ x,
                                                const float* __restrict__ W,
                                                const float* __restrict__ a,
                                                short* __restrict__ HT2,
                                                float* __restrict__ sv,
                                                float* __restrict__ tv) {
  __shared__ short WT[128][136];  // pad 8 shorts -> 2-way alias (free, m136)
  const int tid = threadIdx.x;
  const int w = tid >> 6;
  const int L = tid & 63;
  const int lm = L & 15;
  const int q = L >> 4;
  const int i0 = blockIdx.x * 64;

  f32x4 acc[8];
#pragma unroll
  for (int nn = 0; nn < 8; ++nn) acc[nn] = (f32x4){0.f, 0.f, 0.f, 0.f};

  for (int kc = 0; kc < 256; kc += 128) {
    if (kc) __syncthreads();
#pragma unroll
    for (int p = 0; p < 16; ++p) {
      int idx = p * 256 + tid;  // 0..4095
      int k = idx >> 5;         // 0..127
      int f4 = (idx & 31) * 4;
      float4 v = *(const float4*)&W[(kc + k) * 128 + f4];
      WT[f4 + 0][k] = f2bf(v.x);
      WT[f4 + 1][k] = f2bf(v.y);
      WT[f4 + 2][k] = f2bf(v.z);
      WT[f4 + 3][k] = f2bf(v.w);
    }
    __syncthreads();
#pragma unroll
    for (int ks = 0; ks < 4; ++ks) {
      int row = i0 + 16 * w + lm;
      const float* xp = &x[(size_t)row * 256 + kc + ks * 32 + q * 8];
      float4 xa = *(const float4*)xp;
      float4 xb = *(const float4*)(xp + 4);
      short8 af;
      af[0] = f2bf(xa.x); af[1] = f2bf(xa.y); af[2] = f2bf(xa.z); af[3] = f2bf(xa.w);
      af[4] = f2bf(xb.x); af[5] = f2bf(xb.y); af[6] = f2bf(xb.z); af[7] = f2bf(xb.w);
#pragma unroll
      for (int nn = 0; nn < 8; ++nn) {
        short8 bf = *(const short8*)&WT[nn * 16 + lm][ks * 32 + q * 8];
        acc[nn] = __builtin_amdgcn_mfma_f32_16x16x32_bf16(af, bf, acc[nn], 0, 0, 0);
      }
    }
  }

  const int ib = i0 + 16 * w + 4 * q;  // this thread's 4 output j-rows
  const int tbase = (ib >> 5) * 4096 + (ib & 31);
  float a1v[8], a2v[8];
#pragma unroll
  for (int nn = 0; nn < 8; ++nn) {
    a1v[nn] = a[nn * 16 + lm];
    a2v[nn] = a[128 + nn * 16 + lm];
  }
  float sr[4] = {0.f, 0.f, 0.f, 0.f};
  float tr[4] = {0.f, 0.f, 0.f, 0.f};
#pragma unroll
  for (int nn = 0; nn < 8; ++nn) {
    int f = nn * 16 + lm;
    short4v o;
    o[0] = f2bf(acc[nn][0]);
    o[1] = f2bf(acc[nn][1]);
    o[2] = f2bf(acc[nn][2]);
    o[3] = f2bf(acc[nn][3]);
    *(short4v*)&HT2[tbase + f * 32] = o;
#pragma unroll
    for (int r = 0; r < 4; ++r) {
      sr[r] += acc[nn][r] * a1v[nn];
      tr[r] += acc[nn][r] * a2v[nn];
    }
  }
#pragma unroll
  for (int d = 1; d < 16; d <<= 1) {
#pragma unroll
    for (int r = 0; r < 4; ++r) {
      sr[r] += __shfl_xor(sr[r], d);
      tr[r] += __shfl_xor(tr[r], d);
    }
  }
  if (lm == 0) {
#pragma unroll
    for (int r = 0; r < 4; ++r) {
      sv[ib + r] = sr[r] * LOG2E;
      tv[ib + r] = tr[r] * LOG2E;
    }
  }
}

// ---------------------------------------------------------------------------
// K3: flash-GAT, zero-synchronization variant. 1 wave per block, 32 i-rows,
// S=8 j-splits (32 tiles of 32 j each). B-frags direct from L2-resident
// tiled HT2 (1 KB coalesced per instr; sp-major blockIdx so all blocks on an
// XCD share the same 320 KB tile set). B-frag/tv staged one tile ahead in
// registers; mask one uint4-group ahead. No barriers, no cross-wave
// coupling. 16 KB wave-private LDS used only for the epilogue transpose
// (full-line float4 stores). __launch_bounds__(64,2): 256 regs/wave.
// ---------------------------------------------------------------------------
__global__ __launch_bounds__(64, 2) void k_flash(const unsigned* __restrict__ mask,
                                                 const short* __restrict__ HT2,
                                                 const float* __restrict__ sv,
                                                 const float* __restrict__ tv,
                                                 float* __restrict__ part,
                                                 float* __restrict__ lpart) {
  __shared__ float eps[32 * 128];  // 16 KB, wave-private (1 wave/block)
  const int L = threadIdx.x;
  const int lm = L & 15;
  const int q = L >> 4;
  const int sp = blockIdx.x >> 8;   // j-split (8)
  const int it = blockIdx.x & 255;  // i-tile (256 x 32 rows)
  const int i0 = it * 32;

  const int row0 = i0 + lm;
  const int row1 = row0 + 16;
  const float s0 = sv[row0];
  const float s1 = sv[row1];

  f32x4 acc[2][8];
#pragma unroll
  for (int mm = 0; mm < 2; ++mm)
#pragma unroll
    for (int nn = 0; nn < 8; ++nn) acc[mm][nn] = (f32x4){0.f, 0.f, 0.f, 0.f};
  float l0 = 0.f, l1 = 0.f;

  const int tile0 = sp * 32;  // 32 tiles per split
  // prologue: stage tile0's B-frags + tv, and mask group 0
  const short* tp = &HT2[tile0 * 4096 + (lm * 32 + q * 8)];
  short8 sbf[8];
#pragma unroll
  for (int nn = 0; nn < 8; ++nn) sbf[nn] = *(const short8*)&tp[nn * 512];
  float4 stv0 = *(const float4*)&tv[tile0 * 32 + q * 8];
  float4 stv1 = *(const float4*)&tv[tile0 * 32 + q * 8 + 4];
  uint4 mg0 = *(const uint4*)&mask[row0 * 256 + tile0];
  uint4 mg1 = *(const uint4*)&mask[row1 * 256 + tile0];

  unsigned mwa0[4], mwa1[4];
#pragma unroll 4
  for (int t = 0; t < 32; ++t) {
    // consume staged operands for tile t
    short8 bf[8];
#pragma unroll
    for (int nn = 0; nn < 8; ++nn) bf[nn] = sbf[nn];
    float4 tv0 = stv0, tv1 = stv1;
    if ((t & 3) == 0) {  // consume mask group; prefetch next group
      mwa0[0] = mg0.x; mwa0[1] = mg0.y; mwa0[2] = mg0.z; mwa0[3] = mg0.w;
      mwa1[0] = mg1.x; mwa1[1] = mg1.y; mwa1[2] = mg1.z; mwa1[3] = mg1.w;
      if (t + 4 < 32) {
        mg0 = *(const uint4*)&mask[row0 * 256 + tile0 + t + 4];
        mg1 = *(const uint4*)&mask[row1 * 256 + tile0 + t + 4];
      }
    }
    if (t + 1 < 32) {  // issue tile t+1's loads (in flight over compute)
      const short* np = &HT2[(tile0 + t + 1) * 4096 + (lm * 32 + q * 8)];
#pragma unroll
      for (int nn = 0; nn < 8; ++nn) sbf[nn] = *(const short8*)&np[nn * 512];
      stv0 = *(const float4*)&tv[(tile0 + t + 1) * 32 + q * 8];
      stv1 = *(const float4*)&tv[(tile0 + t + 1) * 32 + q * 8 + 4];
    }

    const unsigned b0 = (mwa0[t & 3] >> (q * 8)) & 0xffu;
    const unsigned b1 = (mwa1[t & 3] >> (q * 8)) & 0xffu;
    float tvl[8] = {tv0.x, tv0.y, tv0.z, tv0.w, tv1.x, tv1.y, tv1.z, tv1.w};
    short8 p0, p1;
#pragma unroll
    for (int e = 0; e < 8; ++e) {
      // logits pre-scaled by log2e; lrelu(v) = max(v, 0.2v)
      float v0 = s0 + tvl[e];
      float e0 = fmaxf(v0, 0.2f * v0);
      float pp0 = (b0 & (1u << e)) ? __builtin_amdgcn_exp2f(e0) : 0.f;
      l0 += pp0;
      p0[e] = f2bf(pp0);
      float v1 = s1 + tvl[e];
      float e1 = fmaxf(v1, 0.2f * v1);
      float pp1 = (b1 & (1u << e)) ? __builtin_amdgcn_exp2f(e1) : 0.f;
      l1 += pp1;
      p1[e] = f2bf(pp1);
    }
#pragma unroll
    for (int nn = 0; nn < 8; ++nn) {
      acc[0][nn] = __builtin_amdgcn_mfma_f32_16x16x32_bf16(p0, bf[nn], acc[0][nn], 0, 0, 0);
      acc[1][nn] = __builtin_amdgcn_mfma_f32_16x16x32_bf16(p1, bf[nn], acc[1][nn], 0, 0, 0);
    }
  }

  // epilogue: wave-private LDS transpose -> contiguous float4 stores.
  // Single wave: ds ordering handled by lgkmcnt, no barrier needed.
#pragma unroll
  for (int mm = 0; mm < 2; ++mm)
#pragma unroll
    for (int nn = 0; nn < 8; ++nn)
#pragma unroll
      for (int r = 0; r < 4; ++r)
        eps[(16 * mm + 4 * q + r) * 128 + nn * 16 + lm] = acc[mm][nn][r];
  float* pbase = part + ((size_t)sp * NR + i0) * 128;
#pragma unroll
  for (int c = 0; c < 16; ++c) {
    int idx = (c * 64 + L) * 4;
    *(float4*)&pbase[idx] = *(const float4*)&eps[idx];
  }

  // denominator: reduce the 4 q-replicas of each row
  l0 += __shfl_xor(l0, 16);
  l0 += __shfl_xor(l0, 32);
  l1 += __shfl_xor(l1, 16);
  l1 += __shfl_xor(l1, 32);
  if (q == 0) {
    lpart[sp * NR + row0] = l0;
    lpart[sp * NR + row1] = l1;
  }
}

// ---------------------------------------------------------------------------
// K4: out[i][f] = sum_sp part / sum_sp lpart   (float4 vectorized)
// ---------------------------------------------------------------------------
__global__ __launch_bounds__(256) void k_reduce(const float* __restrict__ part,
                                                const float* __restrict__ lpart,
                                                float* __restrict__ out, int S) {
  int idx4 = blockIdx.x * 256 + threadIdx.x;
  int idx = idx4 * 4;  // i*128+f
  int i = idx >> 7;
  float4 sum = {0.f, 0.f, 0.f, 0.f};
  for (int sp = 0; sp < S; ++sp) {
    float4 v = *(const float4*)&part[(size_t)sp * (NR * 128) + idx];
    sum.x += v.x; sum.y += v.y; sum.z += v.z; sum.w += v.w;
  }
  float l = 0.f;
  for (int sp = 0; sp < S; ++sp) l += lpart[sp * NR + i];
  float inv = (l > 0.f) ? 1.f / l : 0.f;
  float4 o = {sum.x * inv, sum.y * inv, sum.z * inv, sum.w * inv};
  *(float4*)&out[idx] = o;
}

extern "C" void kernel_launch(void* const* d_in, const int* in_sizes, int n_in,
                              void* d_out, int out_size, void* d_ws, size_t ws_size,
                              hipStream_t stream) {
  const float* x = (const float*)d_in[0];    // 8192 x 256 fp32
  const int* adj = (const int*)d_in[1];      // 8192 x 8192 int32
  const float* W = (const float*)d_in[2];    // 256 x 128 fp32
  const float* a = (const float*)d_in[3];    // 256 x 1 fp32
  float* out = (float*)d_out;                // 8192 x 128 fp32

  char* ws = (char*)d_ws;
  short* HT2 = (short*)(ws + 0);               // 2 MB  bf16 h tiled [256][128][32]
  float* sv = (float*)(ws + 2097152);          // 32 KB
  float* tv = (float*)(ws + 2129920);          // 32 KB
  float* lpart = (float*)(ws + 2162688);       // 8*32 KB = 256 KB
  unsigned* mask = (unsigned*)(ws + 2686976);  // 8 MB bitmask [8192][256 words]
  float* part = (float*)(ws + 11599872);       // 8 * 4 MB = 32 MB

  const int S = 8;  // j-splits: 256 i-tiles x 8 = 2048 one-wave blocks (8/CU)

  hipLaunchKernelGGL(k_pack, dim3((NR * NR / 32) / 256), dim3(256), 0, stream, adj, mask);
  hipLaunchKernelGGL(k_gemm_h, dim3(128), dim3(256), 0, stream, x, W, a, HT2, sv, tv);
  hipLaunchKernelGGL(k_flash, dim3(256 * S), dim3(64), 0, stream, mask, HT2, sv, tv,
                     part, lpart);
  hipLaunchKernelGGL(k_reduce, dim3((NR * 128) / 1024), dim3(256), 0, stream, part,
                     lpart, out, S);
}